// Round 1
// baseline (993.519 us; speedup 1.0000x reference)
//
#include <hip/hip_runtime.h>
#include <hip/hip_bf16.h>

#define EMBED   1024
#define NHEADS  16
#define HDIM    64
#define BATCH   2
#define SEQ     2048
#define NEG_INF (-1.0e9f)

// ---------------------------------------------------------------------------
// Projection GEMM: out[M=B*SEQ][EMBED] = x[M][EMBED] * W^T, W[EMBED out][EMBED in]
// 64x64 tile, 256 threads, 4x4 micro-tile per thread, float4 LDS reads.
// LDS rows padded to 68 floats so 256B-stride row reads don't all hit bank 0.
// ---------------------------------------------------------------------------
__global__ __launch_bounds__(256) void proj_kernel(const float* __restrict__ x,
                                                   const float* __restrict__ w,
                                                   float* __restrict__ out) {
    __shared__ float as[64][68];
    __shared__ float bs[64][68];
    const int tid = threadIdx.x;
    const int tx = tid & 15, ty = tid >> 4;
    const int m0 = blockIdx.x * 64;
    const int c0 = blockIdx.y * 64;
    float acc[4][4] = {};
    for (int k0 = 0; k0 < EMBED; k0 += 64) {
        #pragma unroll
        for (int it = 0; it < 4; ++it) {
            int slot = tid + it * 256;   // 0..1023
            int r = slot >> 4;           // row 0..63
            int kv = slot & 15;          // float4 column
            float4 av = *reinterpret_cast<const float4*>(&x[(size_t)(m0 + r) * EMBED + k0 + kv * 4]);
            *reinterpret_cast<float4*>(&as[r][kv * 4]) = av;
            float4 bv = *reinterpret_cast<const float4*>(&w[(size_t)(c0 + r) * EMBED + k0 + kv * 4]);
            *reinterpret_cast<float4*>(&bs[r][kv * 4]) = bv;
        }
        __syncthreads();
        #pragma unroll
        for (int kk = 0; kk < 64; kk += 4) {
            float4 a4[4], b4[4];
            #pragma unroll
            for (int i = 0; i < 4; ++i) a4[i] = *reinterpret_cast<const float4*>(&as[ty * 4 + i][kk]);
            #pragma unroll
            for (int j = 0; j < 4; ++j) b4[j] = *reinterpret_cast<const float4*>(&bs[tx * 4 + j][kk]);
            #pragma unroll
            for (int i = 0; i < 4; ++i)
                #pragma unroll
                for (int j = 0; j < 4; ++j) {
                    acc[i][j] += a4[i].x * b4[j].x + a4[i].y * b4[j].y
                               + a4[i].z * b4[j].z + a4[i].w * b4[j].w;
                }
        }
        __syncthreads();
    }
    #pragma unroll
    for (int i = 0; i < 4; ++i)
        #pragma unroll
        for (int j = 0; j < 4; ++j)
            out[(size_t)(m0 + ty * 4 + i) * EMBED + c0 + tx * 4 + j] = acc[i][j];
}

// ---------------------------------------------------------------------------
// Flash-style masked LSE: one block = one (b, h, 64-row tile).
// S = beta * Q K^T with diagonal -1e9; online (m, s) per row; 16-lane shfl
// reductions (threads sharing a row are 16 consecutive lanes).
// Contribution to energy accumulated via atomics.
// ---------------------------------------------------------------------------
__global__ __launch_bounds__(256) void attn_lse_kernel(const float* __restrict__ q,
                                                       const float* __restrict__ k,
                                                       const float* __restrict__ betas,
                                                       float* __restrict__ out) {
    __shared__ float qs[64][68];
    __shared__ float ks[64][68];
    __shared__ float bsum;
    const int tid = threadIdx.x;
    const int tx = tid & 15, ty = tid >> 4;
    const int blk = blockIdx.x;        // b*512 + h*32 + rowtile
    const int rowtile = blk & 31;
    const int h = (blk >> 5) & 15;
    const int b = blk >> 9;
    const int n0 = rowtile * 64;
    const float beta = betas[h];

    // stage Q tile [64 rows][64 z]
    #pragma unroll
    for (int it = 0; it < 4; ++it) {
        int slot = tid + it * 256;
        int r = slot >> 4, kv = slot & 15;
        float4 v = *reinterpret_cast<const float4*>(
            &q[((size_t)(b * SEQ + n0 + r)) * EMBED + h * HDIM + kv * 4]);
        *reinterpret_cast<float4*>(&qs[r][kv * 4]) = v;
    }

    float mrun[4], srun[4];
    #pragma unroll
    for (int i = 0; i < 4; ++i) { mrun[i] = -1e30f; srun[i] = 0.f; }

    for (int m0 = 0; m0 < SEQ; m0 += 64) {
        __syncthreads();   // previous-iter ks reads done (also orders first qs use)
        #pragma unroll
        for (int it = 0; it < 4; ++it) {
            int slot = tid + it * 256;
            int r = slot >> 4, kv = slot & 15;
            float4 v = *reinterpret_cast<const float4*>(
                &k[((size_t)(b * SEQ + m0 + r)) * EMBED + h * HDIM + kv * 4]);
            *reinterpret_cast<float4*>(&ks[r][kv * 4]) = v;
        }
        __syncthreads();

        float p[4][4] = {};
        #pragma unroll
        for (int z = 0; z < 64; z += 4) {
            float4 q4[4], k4[4];
            #pragma unroll
            for (int i = 0; i < 4; ++i) q4[i] = *reinterpret_cast<const float4*>(&qs[ty * 4 + i][z]);
            #pragma unroll
            for (int j = 0; j < 4; ++j) k4[j] = *reinterpret_cast<const float4*>(&ks[tx * 4 + j][z]);
            #pragma unroll
            for (int i = 0; i < 4; ++i)
                #pragma unroll
                for (int j = 0; j < 4; ++j)
                    p[i][j] += q4[i].x * k4[j].x + q4[i].y * k4[j].y
                             + q4[i].z * k4[j].z + q4[i].w * k4[j].w;
        }

        // beta-scale, diagonal mask, online-LSE update
        #pragma unroll
        for (int i = 0; i < 4; ++i) {
            const int gr = n0 + ty * 4 + i;
            float pv[4];
            float rmax = -1e30f;
            #pragma unroll
            for (int j = 0; j < 4; ++j) {
                const int gc = m0 + tx * 4 + j;
                float v = beta * p[i][j];
                if (gc == gr) v = NEG_INF;
                pv[j] = v;
                rmax = fmaxf(rmax, v);
            }
            #pragma unroll
            for (int off = 1; off < 16; off <<= 1)
                rmax = fmaxf(rmax, __shfl_xor(rmax, off));
            const float mnew = fmaxf(mrun[i], rmax);
            float part = 0.f;
            #pragma unroll
            for (int j = 0; j < 4; ++j) part += __expf(pv[j] - mnew);
            #pragma unroll
            for (int off = 1; off < 16; off <<= 1)
                part += __shfl_xor(part, off);
            srun[i] = srun[i] * __expf(mrun[i] - mnew) + part;
            mrun[i] = mnew;
        }
    }

    if (tid == 0) bsum = 0.f;
    __syncthreads();
    if (tx == 0) {
        float local = 0.f;
        #pragma unroll
        for (int i = 0; i < 4; ++i) local += mrun[i] + logf(srun[i]);
        atomicAdd(&bsum, local);
    }
    __syncthreads();
    if (tid == 0) {
        atomicAdd(out, -bsum / (beta * (float)(BATCH * SEQ)));
    }
}

extern "C" void kernel_launch(void* const* d_in, const int* in_sizes, int n_in,
                              void* d_out, int out_size, void* d_ws, size_t ws_size,
                              hipStream_t stream) {
    const float* x     = (const float*)d_in[0];
    const float* wk    = (const float*)d_in[1];
    const float* wq    = (const float*)d_in[2];
    const float* betas = (const float*)d_in[3];
    float* out = (float*)d_out;

    float* qws = (float*)d_ws;                                  // [4096][1024] f32 = 16 MB
    float* kws = qws + (size_t)BATCH * SEQ * EMBED;             // 16 MB

    hipMemsetAsync(d_out, 0, sizeof(float), stream);

    dim3 gproj(BATCH * SEQ / 64, EMBED / 64);                   // (64, 16)
    proj_kernel<<<gproj, 256, 0, stream>>>(x, wq, qws);
    proj_kernel<<<gproj, 256, 0, stream>>>(x, wk, kws);

    attn_lse_kernel<<<BATCH * NHEADS * (SEQ / 64), 256, 0, stream>>>(qws, kws, betas, out);
}

// Round 2
// 140.043 us; speedup vs baseline: 7.0944x; 7.0944x over previous
//
#include <hip/hip_runtime.h>
#include <hip/hip_bf16.h>

#define EMBED   1024
#define NHEADS  16
#define HDIM    64
#define BATCH   2
#define SEQ     2048
#define NEG_INF (-1.0e9f)

typedef __attribute__((ext_vector_type(8))) short bf16x8;
typedef __attribute__((ext_vector_type(4))) short bf16x4;
typedef __attribute__((ext_vector_type(4))) float f32x4;
using bf16 = __hip_bfloat16;

// ---------------------------------------------------------------------------
// fp32 -> bf16 cast, optional per-head scale (for wq: bake beta into weights).
// 4 elements per thread.
// ---------------------------------------------------------------------------
__global__ __launch_bounds__(256) void cast_kernel(const float* __restrict__ src,
                                                   bf16* __restrict__ dst,
                                                   const float* __restrict__ betas,
                                                   int per_head, int n) {
    int base = (blockIdx.x * 256 + threadIdx.x) * 4;
    if (base >= n) return;
    float sc = betas ? betas[base / per_head] : 1.0f;
    float4 v = *reinterpret_cast<const float4*>(&src[base]);
    bf16 o[4];
    o[0] = __float2bfloat16(v.x * sc);
    o[1] = __float2bfloat16(v.y * sc);
    o[2] = __float2bfloat16(v.z * sc);
    o[3] = __float2bfloat16(v.w * sc);
    *reinterpret_cast<bf16x4*>(&dst[base]) = *reinterpret_cast<const bf16x4*>(o);
}

// ---------------------------------------------------------------------------
// Projection GEMM via MFMA: out[M=4096][1024] = Xb[4096][1024] * Wb[1024][1024]^T
// (both operands row-major along k -> load A and B fragments identically; the
//  per-lane k-permutation cancels). 128x128 tile, 4 waves (2x2), each wave
//  64x64 = 4x4 fragments of 16x16x32. LDS rows padded to 72 bf16 (144 B) so
//  stride-16-row ds_read_b128 is only 2-way (free).
// ---------------------------------------------------------------------------
__global__ __launch_bounds__(256) void proj_mfma(const bf16* __restrict__ xb,
                                                 const bf16* __restrict__ wb,
                                                 bf16* __restrict__ outb) {
    __shared__ __align__(16) bf16 Xs[128][72];
    __shared__ __align__(16) bf16 Ws[128][72];
    const int tid  = threadIdx.x;
    const int lane = tid & 63;
    const int wave = tid >> 6;
    const int wr = wave >> 1, wc = wave & 1;
    const int m0 = blockIdx.x * 128;
    const int n0 = blockIdx.y * 128;

    f32x4 acc[4][4] = {};

    for (int k0 = 0; k0 < EMBED; k0 += 64) {
        __syncthreads();
        #pragma unroll
        for (int it = 0; it < 4; ++it) {
            int slot = tid + it * 256;      // 0..1023
            int r  = slot >> 3;             // 0..127
            int c8 = slot & 7;              // 16-byte chunk
            bf16x8 xv = *reinterpret_cast<const bf16x8*>(&xb[(size_t)(m0 + r) * EMBED + k0 + c8 * 8]);
            *reinterpret_cast<bf16x8*>(&Xs[r][c8 * 8]) = xv;
            bf16x8 wv = *reinterpret_cast<const bf16x8*>(&wb[(size_t)(n0 + r) * EMBED + k0 + c8 * 8]);
            *reinterpret_cast<bf16x8*>(&Ws[r][c8 * 8]) = wv;
        }
        __syncthreads();
        #pragma unroll
        for (int ks = 0; ks < 2; ++ks) {
            bf16x8 af[4], bf_[4];
            #pragma unroll
            for (int a = 0; a < 4; ++a)
                af[a] = *reinterpret_cast<const bf16x8*>(&Xs[wr * 64 + a * 16 + (lane & 15)][ks * 32 + (lane >> 4) * 8]);
            #pragma unroll
            for (int b2 = 0; b2 < 4; ++b2)
                bf_[b2] = *reinterpret_cast<const bf16x8*>(&Ws[wc * 64 + b2 * 16 + (lane & 15)][ks * 32 + (lane >> 4) * 8]);
            #pragma unroll
            for (int a = 0; a < 4; ++a)
                #pragma unroll
                for (int b2 = 0; b2 < 4; ++b2)
                    acc[a][b2] = __builtin_amdgcn_mfma_f32_16x16x32_bf16(af[a], bf_[b2], acc[a][b2], 0, 0, 0);
        }
    }
    // C/D layout: col = lane&15 (out channel), row = (lane>>4)*4 + j (x row)
    #pragma unroll
    for (int a = 0; a < 4; ++a)
        #pragma unroll
        for (int b2 = 0; b2 < 4; ++b2)
            #pragma unroll
            for (int j = 0; j < 4; ++j) {
                int row = m0 + wr * 64 + a * 16 + (lane >> 4) * 4 + j;
                int col = n0 + wc * 64 + b2 * 16 + (lane & 15);
                outb[(size_t)row * EMBED + col] = __float2bfloat16(acc[a][b2][j]);
            }
}

// ---------------------------------------------------------------------------
// Flash-LSE via MFMA. One block = one (b, h, 128-row q tile); 4 waves, each
// owns 32 q rows. Q fragments live in registers for the whole kernel; K
// fragments are loaded straight from global (K per head = 256 KB, L2-fits).
// mfma(A=K, B=Q) -> D[col=lane&15 -> q row, row=(lane>>4)*4+j -> k row].
// Online (m, s) per q row; cross-lane reduce over the 4 stride-16 groups.
// ---------------------------------------------------------------------------
__global__ __launch_bounds__(256) void attn_lse_mfma(const bf16* __restrict__ q,
                                                     const bf16* __restrict__ k,
                                                     const float* __restrict__ betas,
                                                     float* __restrict__ out) {
    const int tid  = threadIdx.x;
    const int lane = tid & 63;
    const int wave = tid >> 6;
    const int blk = blockIdx.x;          // b*256 + h*16 + qt
    const int qt = blk & 15;
    const int h  = (blk >> 4) & 15;
    const int b  = blk >> 8;
    const int n0 = qt * 128 + wave * 32; // this wave's q-row base (within seq)
    const float beta = betas[h];

    const bf16* qbase = &q[(size_t)(b * SEQ) * EMBED + h * HDIM];
    const bf16* kbase = &k[(size_t)(b * SEQ) * EMBED + h * HDIM];

    // Q fragments qf[qb][ks]: row = n0 + qb*16 + (lane&15), k-chunk (lane>>4)*8
    bf16x8 qf[2][2];
    #pragma unroll
    for (int qb = 0; qb < 2; ++qb)
        #pragma unroll
        for (int ks = 0; ks < 2; ++ks)
            qf[qb][ks] = *reinterpret_cast<const bf16x8*>(
                &qbase[(size_t)(n0 + qb * 16 + (lane & 15)) * EMBED + ks * 32 + (lane >> 4) * 8]);

    float mrun[2] = {-1e30f, -1e30f};
    float srun[2] = {0.f, 0.f};

    for (int m0 = 0; m0 < SEQ; m0 += 64) {
        bf16x8 kf[4][2];
        #pragma unroll
        for (int kb = 0; kb < 4; ++kb)
            #pragma unroll
            for (int ks = 0; ks < 2; ++ks)
                kf[kb][ks] = *reinterpret_cast<const bf16x8*>(
                    &kbase[(size_t)(m0 + kb * 16 + (lane & 15)) * EMBED + ks * 32 + (lane >> 4) * 8]);

        f32x4 acc[4][2] = {};
        #pragma unroll
        for (int kb = 0; kb < 4; ++kb)
            #pragma unroll
            for (int qb = 0; qb < 2; ++qb)
                #pragma unroll
                for (int ks = 0; ks < 2; ++ks)
                    acc[kb][qb] = __builtin_amdgcn_mfma_f32_16x16x32_bf16(kf[kb][ks], qf[qb][ks], acc[kb][qb], 0, 0, 0);

        #pragma unroll
        for (int qb = 0; qb < 2; ++qb) {
            const int qrow = n0 + qb * 16 + (lane & 15);
            float sv[16];
            float tmax = -1e30f;
            #pragma unroll
            for (int kb = 0; kb < 4; ++kb)
                #pragma unroll
                for (int j = 0; j < 4; ++j) {
                    int kcol = m0 + kb * 16 + (lane >> 4) * 4 + j;
                    float v = acc[kb][qb][j];
                    if (kcol == qrow) v = NEG_INF;
                    sv[kb * 4 + j] = v;
                    tmax = fmaxf(tmax, v);
                }
            tmax = fmaxf(tmax, __shfl_xor(tmax, 16));
            tmax = fmaxf(tmax, __shfl_xor(tmax, 32));
            const float mnew = fmaxf(mrun[qb], tmax);
            float psum = 0.f;
            #pragma unroll
            for (int t = 0; t < 16; ++t) psum += __expf(sv[t] - mnew);
            psum += __shfl_xor(psum, 16);
            psum += __shfl_xor(psum, 32);
            srun[qb] = srun[qb] * __expf(mrun[qb] - mnew) + psum;
            mrun[qb] = mnew;
        }
    }

    // lse per q row (replicated across the 4 lane groups); sum over 16 rows x 2 qb
    float lsum = (mrun[0] + logf(srun[0])) + (mrun[1] + logf(srun[1]));
    lsum += __shfl_xor(lsum, 1);
    lsum += __shfl_xor(lsum, 2);
    lsum += __shfl_xor(lsum, 4);
    lsum += __shfl_xor(lsum, 8);

    __shared__ float bsum[4];
    if (lane == 0) bsum[wave] = lsum;
    __syncthreads();
    if (tid == 0) {
        float tot = bsum[0] + bsum[1] + bsum[2] + bsum[3];
        atomicAdd(out, -tot / (beta * (float)(BATCH * SEQ)));
    }
}

extern "C" void kernel_launch(void* const* d_in, const int* in_sizes, int n_in,
                              void* d_out, int out_size, void* d_ws, size_t ws_size,
                              hipStream_t stream) {
    const float* x     = (const float*)d_in[0];
    const float* wk    = (const float*)d_in[1];
    const float* wq    = (const float*)d_in[2];
    const float* betas = (const float*)d_in[3];
    float* out = (float*)d_out;

    const size_t NX = (size_t)BATCH * SEQ * EMBED;   // 4,194,304
    const size_t NW = (size_t)EMBED * EMBED;         // 1,048,576

    bf16* xb  = (bf16*)d_ws;            // 8 MB
    bf16* wqb = xb + NX;                // 2 MB
    bf16* wkb = wqb + NW;               // 2 MB
    bf16* qb  = wkb + NW;               // 8 MB
    bf16* kb  = qb + NX;                // 8 MB

    hipMemsetAsync(d_out, 0, sizeof(float), stream);

    cast_kernel<<<(int)(NX / 4 / 256), 256, 0, stream>>>(x, xb, nullptr, 1, (int)NX);
    cast_kernel<<<(int)(NW / 4 / 256), 256, 0, stream>>>(wq, wqb, betas, HDIM * EMBED, (int)NW);
    cast_kernel<<<(int)(NW / 4 / 256), 256, 0, stream>>>(wk, wkb, nullptr, 1, (int)NW);

    dim3 gproj(BATCH * SEQ / 128, EMBED / 128);      // (32, 8)
    proj_mfma<<<gproj, 256, 0, stream>>>(xb, wqb, qb);
    proj_mfma<<<gproj, 256, 0, stream>>>(xb, wkb, kb);

    attn_lse_mfma<<<BATCH * NHEADS * (SEQ / 128), 256, 0, stream>>>(qb, kb, betas, out);
}

// Round 3
// 94.705 us; speedup vs baseline: 10.4907x; 1.4787x over previous
//
#include <hip/hip_runtime.h>
#include <hip/hip_bf16.h>

#define EMBED   1024
#define NHEADS  16
#define HDIM    64
#define BATCH   2
#define SEQ     2048
#define KSPLIT  4
#define LOG2E   1.44269504088896340736f

typedef __attribute__((ext_vector_type(8))) short bf16x8;
typedef __attribute__((ext_vector_type(4))) short bf16x4;
typedef __attribute__((ext_vector_type(4))) float f32x4;
using bf16 = __hip_bfloat16;

// async global->LDS, 16B per lane; LDS dest is wave-uniform base + lane*16
__device__ __forceinline__ void gload_lds16(const bf16* g, bf16* l) {
    __builtin_amdgcn_global_load_lds(
        (const __attribute__((address_space(1))) void*)g,
        (__attribute__((address_space(3))) void*)l,
        16, 0, 0);
}

// ---------------------------------------------------------------------------
// fp32 -> bf16 cast; optional per-head scale (wq gets beta*log2e baked in so
// attention scores come out as s*log2(e) and the inner loop is pure exp2f).
// ---------------------------------------------------------------------------
__global__ __launch_bounds__(256) void cast_kernel(const float* __restrict__ src,
                                                   bf16* __restrict__ dst,
                                                   const float* __restrict__ betas,
                                                   int per_head, float extra, int n) {
    int base = (blockIdx.x * 256 + threadIdx.x) * 4;
    if (base >= n) return;
    float sc = (betas ? betas[base / per_head] : 1.0f) * extra;
    float4 v = *reinterpret_cast<const float4*>(&src[base]);
    bf16 o[4];
    o[0] = __float2bfloat16(v.x * sc);
    o[1] = __float2bfloat16(v.y * sc);
    o[2] = __float2bfloat16(v.z * sc);
    o[3] = __float2bfloat16(v.w * sc);
    *reinterpret_cast<bf16x4*>(&dst[base]) = *reinterpret_cast<const bf16x4*>(o);
}

// ---------------------------------------------------------------------------
// Fused q+k projection GEMM via MFMA, m97-style: 128x128 tile, 4 waves,
// global_load_lds width-16 staging into linear LDS [128][64].
// blockIdx.y < 8 -> wq/qout, else wk/kout.
// ---------------------------------------------------------------------------
__global__ __launch_bounds__(256) void proj_mfma(const bf16* __restrict__ xb,
                                                 const bf16* __restrict__ wqb,
                                                 const bf16* __restrict__ wkb,
                                                 bf16* __restrict__ qout,
                                                 bf16* __restrict__ kout) {
    __shared__ __align__(16) bf16 As[128][64];
    __shared__ __align__(16) bf16 Bs[128][64];
    const int tid  = threadIdx.x;
    const int lane = tid & 63;
    const int wave = tid >> 6;
    const int wr = wave >> 1, wc = wave & 1;
    const int m0 = blockIdx.x * 128;
    const bool isq = (blockIdx.y < 8);
    const int n0 = (blockIdx.y & 7) * 128;
    const bf16* wb = isq ? wqb : wkb;
    bf16* outb = isq ? qout : kout;
    const int srow = lane >> 3;          // row within 8-row chunk
    const int scol = (lane & 7) * 8;     // element col of this lane's 16B

    f32x4 acc[4][4] = {};

    for (int k0 = 0; k0 < EMBED; k0 += 64) {
        #pragma unroll
        for (int i = 0; i < 4; ++i) {
            int j = wave * 4 + i;        // chunk 0..15 (8 rows each)
            gload_lds16(&xb[(size_t)(m0 + j * 8 + srow) * EMBED + k0 + scol], &As[j * 8][0]);
            gload_lds16(&wb[(size_t)(n0 + j * 8 + srow) * EMBED + k0 + scol], &Bs[j * 8][0]);
        }
        __syncthreads();                 // drains vmcnt: staging complete
        #pragma unroll
        for (int ks = 0; ks < 2; ++ks) {
            bf16x8 af[4], bfr[4];
            #pragma unroll
            for (int a = 0; a < 4; ++a)
                af[a] = *reinterpret_cast<const bf16x8*>(&As[wr * 64 + a * 16 + (lane & 15)][ks * 32 + (lane >> 4) * 8]);
            #pragma unroll
            for (int b2 = 0; b2 < 4; ++b2)
                bfr[b2] = *reinterpret_cast<const bf16x8*>(&Bs[wc * 64 + b2 * 16 + (lane & 15)][ks * 32 + (lane >> 4) * 8]);
            #pragma unroll
            for (int a = 0; a < 4; ++a)
                #pragma unroll
                for (int b2 = 0; b2 < 4; ++b2)
                    acc[a][b2] = __builtin_amdgcn_mfma_f32_16x16x32_bf16(af[a], bfr[b2], acc[a][b2], 0, 0, 0);
        }
        __syncthreads();                 // reads done before next overwrite
    }
    #pragma unroll
    for (int a = 0; a < 4; ++a)
        #pragma unroll
        for (int b2 = 0; b2 < 4; ++b2)
            #pragma unroll
            for (int j = 0; j < 4; ++j) {
                int row = m0 + wr * 64 + a * 16 + (lane >> 4) * 4 + j;
                int col = n0 + wc * 64 + b2 * 16 + (lane & 15);
                outb[(size_t)row * EMBED + col] = __float2bfloat16(acc[a][b2][j]);
            }
}

// ---------------------------------------------------------------------------
// Masked exp-sum via MFMA (m=0 fixed: scores tiny, no overflow possible).
// One block = (b, h, 128-row q tile, k-range of 512); 4 waves, 32 q rows each.
// Q fragments in registers; K tile staged in padded LDS (shared by 4 waves).
// Scores arrive pre-scaled by beta*log2e -> psum += exp2(score), diag masked.
// Partial sums written (no atomics) to partial[row][KSPLIT].
// ---------------------------------------------------------------------------
__global__ __launch_bounds__(256) void attn_sum_mfma(const bf16* __restrict__ q,
                                                     const bf16* __restrict__ k,
                                                     float* __restrict__ partial) {
    __shared__ __align__(16) bf16 Ks[64][72];   // +8 pad: conflict-free reads
    const int tid  = threadIdx.x;
    const int lane = tid & 63;
    const int wave = tid >> 6;
    const int blk = blockIdx.x;          // (((b*16+h)*16)+qt)*KSPLIT + kt
    const int kt = blk & (KSPLIT - 1);
    const int qt = (blk >> 2) & 15;
    const int h  = (blk >> 6) & 15;
    const int b  = blk >> 10;
    const int n0 = qt * 128 + wave * 32;
    const bf16* qbase = q + (size_t)(b * SEQ) * EMBED + h * HDIM;
    const bf16* kbase = k + (size_t)(b * SEQ) * EMBED + h * HDIM;

    bf16x8 qf[2][2];
    #pragma unroll
    for (int qb = 0; qb < 2; ++qb)
        #pragma unroll
        for (int ks = 0; ks < 2; ++ks)
            qf[qb][ks] = *reinterpret_cast<const bf16x8*>(
                &qbase[(size_t)(n0 + qb * 16 + (lane & 15)) * EMBED + ks * 32 + (lane >> 4) * 8]);

    float psum[2] = {0.f, 0.f};

    for (int m0 = kt * (SEQ / KSPLIT); m0 < (kt + 1) * (SEQ / KSPLIT); m0 += 64) {
        __syncthreads();                 // prior reads of Ks done
        #pragma unroll
        for (int it = 0; it < 2; ++it) {
            int slot = tid + it * 256;   // 0..511
            int r = slot >> 3, c8 = slot & 7;
            bf16x8 v = *reinterpret_cast<const bf16x8*>(&kbase[(size_t)(m0 + r) * EMBED + c8 * 8]);
            *reinterpret_cast<bf16x8*>(&Ks[r][c8 * 8]) = v;
        }
        __syncthreads();

        f32x4 acc[4][2] = {};
        #pragma unroll
        for (int ks = 0; ks < 2; ++ks) {
            bf16x8 kf[4];
            #pragma unroll
            for (int kb = 0; kb < 4; ++kb)
                kf[kb] = *reinterpret_cast<const bf16x8*>(&Ks[kb * 16 + (lane & 15)][ks * 32 + (lane >> 4) * 8]);
            #pragma unroll
            for (int kb = 0; kb < 4; ++kb)
                #pragma unroll
                for (int qb = 0; qb < 2; ++qb)
                    acc[kb][qb] = __builtin_amdgcn_mfma_f32_16x16x32_bf16(kf[kb], qf[qb][ks], acc[kb][qb], 0, 0, 0);
        }

        #pragma unroll
        for (int qb = 0; qb < 2; ++qb) {
            const int qrow = n0 + qb * 16 + (lane & 15);
            #pragma unroll
            for (int kb = 0; kb < 4; ++kb)
                #pragma unroll
                for (int j = 0; j < 4; ++j) {
                    int kcol = m0 + kb * 16 + (lane >> 4) * 4 + j;
                    float e = exp2f(acc[kb][qb][j]);
                    psum[qb] += (kcol == qrow) ? 0.f : e;
                }
        }
    }

    #pragma unroll
    for (int qb = 0; qb < 2; ++qb) {
        psum[qb] += __shfl_xor(psum[qb], 16);
        psum[qb] += __shfl_xor(psum[qb], 32);
    }
    if (lane < 16) {
        size_t rbase = (size_t)(b * NHEADS + h) * SEQ + n0 + lane;
        partial[(rbase + 0)  * KSPLIT + kt] = psum[0];
        partial[(rbase + 16) * KSPLIT + kt] = psum[1];
    }
}

// ---------------------------------------------------------------------------
// lse = log(sum of KSPLIT partials) per row; energy = -sum(lse/beta)/(B*N).
// ---------------------------------------------------------------------------
__global__ __launch_bounds__(256) void finalize_kernel(const float* __restrict__ partial,
                                                       const float* __restrict__ betas,
                                                       float* __restrict__ out) {
    const int idx = blockIdx.x * 256 + threadIdx.x;    // 0..65535
    const float4 p = *reinterpret_cast<const float4*>(&partial[(size_t)idx * KSPLIT]);
    const int h = (idx >> 11) & 15;                    // idx = (b*16+h)*2048 + n
    float c = -logf(p.x + p.y + p.z + p.w) / (betas[h] * (float)(BATCH * SEQ));
    #pragma unroll
    for (int off = 1; off < 64; off <<= 1) c += __shfl_xor(c, off);
    __shared__ float ws[4];
    const int lane = threadIdx.x & 63, wave = threadIdx.x >> 6;
    if (lane == 0) ws[wave] = c;
    __syncthreads();
    if (threadIdx.x == 0) atomicAdd(out, ws[0] + ws[1] + ws[2] + ws[3]);
}

extern "C" void kernel_launch(void* const* d_in, const int* in_sizes, int n_in,
                              void* d_out, int out_size, void* d_ws, size_t ws_size,
                              hipStream_t stream) {
    const float* x     = (const float*)d_in[0];
    const float* wk    = (const float*)d_in[1];
    const float* wq    = (const float*)d_in[2];
    const float* betas = (const float*)d_in[3];
    float* out = (float*)d_out;

    const size_t NX = (size_t)BATCH * SEQ * EMBED;   // 4,194,304
    const size_t NW = (size_t)EMBED * EMBED;         // 1,048,576

    bf16* xb   = (bf16*)d_ws;                        // 8 MB
    bf16* wqb  = xb + NX;                            // 2 MB
    bf16* wkb  = wqb + NW;                           // 2 MB
    bf16* qb   = wkb + NW;                           // 8 MB
    bf16* kb   = qb + NX;                            // 8 MB
    float* prt = (float*)(kb + NX);                  // 1 MB: [B*H*SEQ][KSPLIT]

    hipMemsetAsync(d_out, 0, sizeof(float), stream);

    cast_kernel<<<(int)(NX / 4 / 256), 256, 0, stream>>>(x, xb, nullptr, 1, 1.0f, (int)NX);
    cast_kernel<<<(int)(NW / 4 / 256), 256, 0, stream>>>(wq, wqb, betas, HDIM * EMBED, LOG2E, (int)NW);
    cast_kernel<<<(int)(NW / 4 / 256), 256, 0, stream>>>(wk, wkb, nullptr, 1, 1.0f, (int)NW);

    dim3 gproj(BATCH * SEQ / 128, 2 * EMBED / 128);  // (32, 16)
    proj_mfma<<<gproj, 256, 0, stream>>>(xb, wqb, wkb, qb, kb);

    attn_sum_mfma<<<BATCH * NHEADS * 16 * KSPLIT, 256, 0, stream>>>(qb, kb, prt);

    finalize_kernel<<<BATCH * NHEADS * SEQ / 256, 256, 0, stream>>>(prt, betas, out);
}

// Round 4
// 74.689 us; speedup vs baseline: 13.3021x; 1.2680x over previous
//
#include <hip/hip_runtime.h>
#include <hip/hip_bf16.h>

#define EMBED   1024
#define NHEADS  16
#define HDIM    64
#define BATCH   2
#define SEQ     2048
#define KSPLIT  4
#define LOG2E   1.44269504088896340736f

typedef __attribute__((ext_vector_type(8))) short bf16x8;
typedef __attribute__((ext_vector_type(4))) short bf16x4;
typedef __attribute__((ext_vector_type(4))) float f32x4;
using bf16 = __hip_bfloat16;

#if __has_builtin(__builtin_amdgcn_exp2f)
__device__ __forceinline__ float fast_exp2(float x) { return __builtin_amdgcn_exp2f(x); }
#else
__device__ __forceinline__ float fast_exp2(float x) {
    float r; asm("v_exp_f32 %0, %1" : "=v"(r) : "v"(x)); return r;
}
#endif

// async global->LDS, 16B per lane; LDS dest is wave-uniform base + lane*16
__device__ __forceinline__ void gload_lds16(const bf16* g, bf16* l) {
    __builtin_amdgcn_global_load_lds(
        (const __attribute__((address_space(1))) void*)g,
        (__attribute__((address_space(3))) void*)l,
        16, 0, 0);
}

// ---------------------------------------------------------------------------
// Fused fp32->bf16 prep: region 0 = x (scale 1), region 1 = wq (scale
// beta[h]*log2e, baking the beta scale AND the exp2 conversion into q),
// region 2 = wk (scale 1). One launch instead of three.
// ---------------------------------------------------------------------------
__global__ __launch_bounds__(256) void prep_kernel(const float* __restrict__ x,
                                                   const float* __restrict__ wq,
                                                   const float* __restrict__ wk,
                                                   const float* __restrict__ betas,
                                                   bf16* __restrict__ xb,
                                                   bf16* __restrict__ wqb,
                                                   bf16* __restrict__ wkb) {
    const size_t NX = (size_t)BATCH * SEQ * EMBED;
    const size_t NW = (size_t)EMBED * EMBED;
    size_t i4 = ((size_t)blockIdx.x * 256 + threadIdx.x) * 4;
    const float* src;
    bf16* dst;
    float sc;
    if (i4 < NX)            { src = x  + i4; dst = xb  + i4; sc = 1.0f; }
    else if (i4 < NX + NW)  { size_t i = i4 - NX; src = wq + i; dst = wqb + i;
                              sc = betas[i >> 16] * LOG2E; }   // 64*1024 elems/head
    else                    { size_t i = i4 - NX - NW; src = wk + i; dst = wkb + i; sc = 1.0f; }
    float4 v = *reinterpret_cast<const float4*>(src);
    bf16 o[4];
    o[0] = __float2bfloat16(v.x * sc);
    o[1] = __float2bfloat16(v.y * sc);
    o[2] = __float2bfloat16(v.z * sc);
    o[3] = __float2bfloat16(v.w * sc);
    *reinterpret_cast<bf16x4*>(dst) = *reinterpret_cast<const bf16x4*>(o);
}

// ---------------------------------------------------------------------------
// Fused q+k projection GEMM via MFMA, m97-style: 128x128 tile, 4 waves,
// global_load_lds width-16 staging into linear LDS [128][64].
// blockIdx.y < 8 -> wq/qout, else wk/kout.
// ---------------------------------------------------------------------------
__global__ __launch_bounds__(256) void proj_mfma(const bf16* __restrict__ xb,
                                                 const bf16* __restrict__ wqb,
                                                 const bf16* __restrict__ wkb,
                                                 bf16* __restrict__ qout,
                                                 bf16* __restrict__ kout) {
    __shared__ __align__(16) bf16 As[128][64];
    __shared__ __align__(16) bf16 Bs[128][64];
    const int tid  = threadIdx.x;
    const int lane = tid & 63;
    const int wave = tid >> 6;
    const int wr = wave >> 1, wc = wave & 1;
    const int m0 = blockIdx.x * 128;
    const bool isq = (blockIdx.y < 8);
    const int n0 = (blockIdx.y & 7) * 128;
    const bf16* wb = isq ? wqb : wkb;
    bf16* outb = isq ? qout : kout;
    const int srow = lane >> 3;          // row within 8-row chunk
    const int scol = (lane & 7) * 8;     // element col of this lane's 16B

    f32x4 acc[4][4] = {};

    for (int k0 = 0; k0 < EMBED; k0 += 64) {
        #pragma unroll
        for (int i = 0; i < 4; ++i) {
            int j = wave * 4 + i;        // chunk 0..15 (8 rows each)
            gload_lds16(&xb[(size_t)(m0 + j * 8 + srow) * EMBED + k0 + scol], &As[j * 8][0]);
            gload_lds16(&wb[(size_t)(n0 + j * 8 + srow) * EMBED + k0 + scol], &Bs[j * 8][0]);
        }
        __syncthreads();                 // drains vmcnt: staging complete
        #pragma unroll
        for (int ks = 0; ks < 2; ++ks) {
            bf16x8 af[4], bfr[4];
            #pragma unroll
            for (int a = 0; a < 4; ++a)
                af[a] = *reinterpret_cast<const bf16x8*>(&As[wr * 64 + a * 16 + (lane & 15)][ks * 32 + (lane >> 4) * 8]);
            #pragma unroll
            for (int b2 = 0; b2 < 4; ++b2)
                bfr[b2] = *reinterpret_cast<const bf16x8*>(&Bs[wc * 64 + b2 * 16 + (lane & 15)][ks * 32 + (lane >> 4) * 8]);
            #pragma unroll
            for (int a = 0; a < 4; ++a)
                #pragma unroll
                for (int b2 = 0; b2 < 4; ++b2)
                    acc[a][b2] = __builtin_amdgcn_mfma_f32_16x16x32_bf16(af[a], bfr[b2], acc[a][b2], 0, 0, 0);
        }
        __syncthreads();                 // reads done before next overwrite
    }
    #pragma unroll
    for (int a = 0; a < 4; ++a)
        #pragma unroll
        for (int b2 = 0; b2 < 4; ++b2)
            #pragma unroll
            for (int j = 0; j < 4; ++j) {
                int row = m0 + wr * 64 + a * 16 + (lane >> 4) * 4 + j;
                int col = n0 + wc * 64 + b2 * 16 + (lane & 15);
                outb[(size_t)row * EMBED + col] = __float2bfloat16(acc[a][b2][j]);
            }
}

// ---------------------------------------------------------------------------
// Masked exp-sum via MFMA (fixed m=0: scores are O(0.05), no overflow).
// One block = (b, h, 128 q rows, 512-k range); 4 waves own 32 q rows each.
// Q fragments in registers; K tile [64][72] staged in LDS (padded: 2-way max).
// T14 split staging: next tile's global loads issue before current compute.
// Raw v_exp_f32; diagonal masked only in wave-uniform diag-intersecting
// iterations. Partials (no atomics) to partial[row][KSPLIT].
// ---------------------------------------------------------------------------
__global__ __launch_bounds__(256) void attn_sum_mfma(const bf16* __restrict__ q,
                                                     const bf16* __restrict__ k,
                                                     float* __restrict__ partial) {
    __shared__ __align__(16) bf16 Ks[64][72];
    const int tid  = threadIdx.x;
    const int lane = tid & 63;
    const int wave = tid >> 6;
    const int blk = blockIdx.x;          // (((b*16+h)*16)+qt)*KSPLIT + kt
    const int kt = blk & (KSPLIT - 1);
    const int qt = (blk >> 2) & 15;
    const int h  = (blk >> 6) & 15;
    const int b  = blk >> 10;
    const int n0 = qt * 128 + wave * 32;
    const bf16* qbase = q + (size_t)(b * SEQ) * EMBED + h * HDIM;
    const bf16* kbase = k + (size_t)(b * SEQ) * EMBED + h * HDIM;

    const int sr = tid >> 3;             // staging row 0..31 (+32 on 2nd chunk)
    const int sc = (tid & 7) * 8;        // staging col

    bf16x8 qf[2][2];
    #pragma unroll
    for (int qb = 0; qb < 2; ++qb)
        #pragma unroll
        for (int ks = 0; ks < 2; ++ks)
            qf[qb][ks] = *reinterpret_cast<const bf16x8*>(
                &qbase[(size_t)(n0 + qb * 16 + (lane & 15)) * EMBED + ks * 32 + (lane >> 4) * 8]);

    f32x4 psv[2] = {};
    const int mbase = kt * (SEQ / KSPLIT);

    bf16x8 stg[2];
    #pragma unroll
    for (int c = 0; c < 2; ++c)
        stg[c] = *reinterpret_cast<const bf16x8*>(&kbase[(size_t)(mbase + c * 32 + sr) * EMBED + sc]);

    for (int it = 0; it < SEQ / KSPLIT / 64; ++it) {
        const int m0 = mbase + it * 64;
        __syncthreads();                 // prior Ks readers done
        #pragma unroll
        for (int c = 0; c < 2; ++c)
            *reinterpret_cast<bf16x8*>(&Ks[c * 32 + sr][sc]) = stg[c];
        __syncthreads();                 // Ks ready
        if (it + 1 < SEQ / KSPLIT / 64) {
            #pragma unroll
            for (int c = 0; c < 2; ++c)  // issue next tile; hides under compute
                stg[c] = *reinterpret_cast<const bf16x8*>(&kbase[(size_t)(m0 + 64 + c * 32 + sr) * EMBED + sc]);
        }

        f32x4 acc[4][2] = {};
        #pragma unroll
        for (int ks = 0; ks < 2; ++ks) {
            bf16x8 kf[4];
            #pragma unroll
            for (int kb = 0; kb < 4; ++kb)
                kf[kb] = *reinterpret_cast<const bf16x8*>(&Ks[kb * 16 + (lane & 15)][ks * 32 + (lane >> 4) * 8]);
            #pragma unroll
            for (int kb = 0; kb < 4; ++kb)
                #pragma unroll
                for (int qb = 0; qb < 2; ++qb)
                    acc[kb][qb] = __builtin_amdgcn_mfma_f32_16x16x32_bf16(kf[kb], qf[qb][ks], acc[kb][qb], 0, 0, 0);
        }

        const bool hasdiag = (m0 < n0 + 32) && (n0 < m0 + 64);
        if (hasdiag) {
            #pragma unroll
            for (int qb = 0; qb < 2; ++qb) {
                const int qrow = n0 + qb * 16 + (lane & 15);
                #pragma unroll
                for (int kb = 0; kb < 4; ++kb)
                    #pragma unroll
                    for (int j = 0; j < 4; ++j) {
                        int kcol = m0 + kb * 16 + (lane >> 4) * 4 + j;
                        float e = fast_exp2(acc[kb][qb][j]);
                        psv[qb][j] += (kcol == qrow) ? 0.f : e;
                    }
            }
        } else {
            #pragma unroll
            for (int qb = 0; qb < 2; ++qb)
                #pragma unroll
                for (int kb = 0; kb < 4; ++kb)
                    #pragma unroll
                    for (int j = 0; j < 4; ++j)
                        psv[qb][j] += fast_exp2(acc[kb][qb][j]);
        }
    }

    #pragma unroll
    for (int qb = 0; qb < 2; ++qb) {
        float psum = (psv[qb][0] + psv[qb][1]) + (psv[qb][2] + psv[qb][3]);
        psum += __shfl_xor(psum, 16);
        psum += __shfl_xor(psum, 32);
        if (lane < 16) {
            size_t rbase = (size_t)(b * NHEADS + h) * SEQ + n0 + qb * 16 + lane;
            partial[rbase * KSPLIT + kt] = psum;
        }
    }
}

// ---------------------------------------------------------------------------
// lse = log(sum of KSPLIT partials) per row; energy = -sum(lse/beta)/(B*N).
// ---------------------------------------------------------------------------
__global__ __launch_bounds__(256) void finalize_kernel(const float* __restrict__ partial,
                                                       const float* __restrict__ betas,
                                                       float* __restrict__ out) {
    const int idx = blockIdx.x * 256 + threadIdx.x;    // 0..65535
    const float4 p = *reinterpret_cast<const float4*>(&partial[(size_t)idx * KSPLIT]);
    const int h = (idx >> 11) & 15;                    // idx = (b*16+h)*2048 + n
    float c = -logf(p.x + p.y + p.z + p.w) / (betas[h] * (float)(BATCH * SEQ));
    #pragma unroll
    for (int off = 1; off < 64; off <<= 1) c += __shfl_xor(c, off);
    __shared__ float ws[4];
    const int lane = threadIdx.x & 63, wave = threadIdx.x >> 6;
    if (lane == 0) ws[wave] = c;
    __syncthreads();
    if (threadIdx.x == 0) atomicAdd(out, ws[0] + ws[1] + ws[2] + ws[3]);
}

extern "C" void kernel_launch(void* const* d_in, const int* in_sizes, int n_in,
                              void* d_out, int out_size, void* d_ws, size_t ws_size,
                              hipStream_t stream) {
    const float* x     = (const float*)d_in[0];
    const float* wk    = (const float*)d_in[1];
    const float* wq    = (const float*)d_in[2];
    const float* betas = (const float*)d_in[3];
    float* out = (float*)d_out;

    const size_t NX = (size_t)BATCH * SEQ * EMBED;   // 4,194,304
    const size_t NW = (size_t)EMBED * EMBED;         // 1,048,576

    bf16* xb   = (bf16*)d_ws;                        // 8 MB
    bf16* wqb  = xb + NX;                            // 2 MB
    bf16* wkb  = wqb + NW;                           // 2 MB
    bf16* qb   = wkb + NW;                           // 8 MB
    bf16* kb   = qb + NX;                            // 8 MB
    float* prt = (float*)(kb + NX);                  // 1 MB: [B*H*SEQ][KSPLIT]

    hipMemsetAsync(d_out, 0, sizeof(float), stream);

    prep_kernel<<<(int)((NX + 2 * NW) / 4 / 256), 256, 0, stream>>>(x, wq, wk, betas, xb, wqb, wkb);

    dim3 gproj(BATCH * SEQ / 128, 2 * EMBED / 128);  // (32, 16)
    proj_mfma<<<gproj, 256, 0, stream>>>(xb, wqb, wkb, qb, kb);

    attn_sum_mfma<<<BATCH * NHEADS * 16 * KSPLIT, 256, 0, stream>>>(qb, kb, prt);

    finalize_kernel<<<BATCH * NHEADS * SEQ / 256, 256, 0, stream>>>(prt, betas, out);
}

// Round 5
// 70.181 us; speedup vs baseline: 14.1565x; 1.0642x over previous
//
#include <hip/hip_runtime.h>
#include <hip/hip_bf16.h>

#define EMBED   1024
#define NHEADS  16
#define HDIM    64
#define BATCH   2
#define SEQ     2048
#define KSPLIT  4
#define LOG2E   1.44269504088896340736f

typedef __attribute__((ext_vector_type(8))) short bf16x8;
typedef __attribute__((ext_vector_type(4))) short bf16x4;
typedef __attribute__((ext_vector_type(4))) float f32x4;
typedef __attribute__((ext_vector_type(16))) float f32x16;
using bf16 = __hip_bfloat16;

#if __has_builtin(__builtin_amdgcn_exp2f)
__device__ __forceinline__ float fast_exp2(float x) { return __builtin_amdgcn_exp2f(x); }
#else
__device__ __forceinline__ float fast_exp2(float x) {
    float r; asm("v_exp_f32 %0, %1" : "=v"(r) : "v"(x)); return r;
}
#endif

// async global->LDS, 16B per lane; LDS dest is wave-uniform base + lane*16
__device__ __forceinline__ void gload_lds16(const bf16* g, bf16* l) {
    __builtin_amdgcn_global_load_lds(
        (const __attribute__((address_space(1))) void*)g,
        (__attribute__((address_space(3))) void*)l,
        16, 0, 0);
}

// ---------------------------------------------------------------------------
// Fused fp32->bf16 prep: x (scale 1), wq (scale beta*log2e), wk (scale 1).
// Thread (0,0) also zeroes the energy accumulator (replaces a memset launch;
// in-stream ordering makes it visible to finalize_kernel's atomics).
// ---------------------------------------------------------------------------
__global__ __launch_bounds__(256) void prep_kernel(const float* __restrict__ x,
                                                   const float* __restrict__ wq,
                                                   const float* __restrict__ wk,
                                                   const float* __restrict__ betas,
                                                   bf16* __restrict__ xb,
                                                   bf16* __restrict__ wqb,
                                                   bf16* __restrict__ wkb,
                                                   float* __restrict__ out) {
    const size_t NX = (size_t)BATCH * SEQ * EMBED;
    const size_t NW = (size_t)EMBED * EMBED;
    if (blockIdx.x == 0 && threadIdx.x == 0) out[0] = 0.f;
    size_t i4 = ((size_t)blockIdx.x * 256 + threadIdx.x) * 4;
    const float* src;
    bf16* dst;
    float sc;
    if (i4 < NX)            { src = x  + i4; dst = xb  + i4; sc = 1.0f; }
    else if (i4 < NX + NW)  { size_t i = i4 - NX; src = wq + i; dst = wqb + i;
                              sc = betas[i >> 16] * LOG2E; }   // 64*1024 elems/head
    else                    { size_t i = i4 - NX - NW; src = wk + i; dst = wkb + i; sc = 1.0f; }
    float4 v = *reinterpret_cast<const float4*>(src);
    bf16 o[4];
    o[0] = __float2bfloat16(v.x * sc);
    o[1] = __float2bfloat16(v.y * sc);
    o[2] = __float2bfloat16(v.z * sc);
    o[3] = __float2bfloat16(v.w * sc);
    *reinterpret_cast<bf16x4*>(dst) = *reinterpret_cast<const bf16x4*>(o);
}

// ---------------------------------------------------------------------------
// Fused q+k projection GEMM via MFMA, m97-style: 128x128 tile, 4 waves,
// global_load_lds width-16 staging into linear LDS [128][64].
// blockIdx.y < 8 -> wq/qout, else wk/kout.
// ---------------------------------------------------------------------------
__global__ __launch_bounds__(256) void proj_mfma(const bf16* __restrict__ xb,
                                                 const bf16* __restrict__ wqb,
                                                 const bf16* __restrict__ wkb,
                                                 bf16* __restrict__ qout,
                                                 bf16* __restrict__ kout) {
    __shared__ __align__(16) bf16 As[128][64];
    __shared__ __align__(16) bf16 Bs[128][64];
    const int tid  = threadIdx.x;
    const int lane = tid & 63;
    const int wave = tid >> 6;
    const int wr = wave >> 1, wc = wave & 1;
    const int m0 = blockIdx.x * 128;
    const bool isq = (blockIdx.y < 8);
    const int n0 = (blockIdx.y & 7) * 128;
    const bf16* wb = isq ? wqb : wkb;
    bf16* outb = isq ? qout : kout;
    const int srow = lane >> 3;          // row within 8-row chunk
    const int scol = (lane & 7) * 8;     // element col of this lane's 16B

    f32x4 acc[4][4] = {};

    for (int k0 = 0; k0 < EMBED; k0 += 64) {
        #pragma unroll
        for (int i = 0; i < 4; ++i) {
            int j = wave * 4 + i;        // chunk 0..15 (8 rows each)
            gload_lds16(&xb[(size_t)(m0 + j * 8 + srow) * EMBED + k0 + scol], &As[j * 8][0]);
            gload_lds16(&wb[(size_t)(n0 + j * 8 + srow) * EMBED + k0 + scol], &Bs[j * 8][0]);
        }
        __syncthreads();                 // drains vmcnt: staging complete
        #pragma unroll
        for (int ks = 0; ks < 2; ++ks) {
            bf16x8 af[4], bfr[4];
            #pragma unroll
            for (int a = 0; a < 4; ++a)
                af[a] = *reinterpret_cast<const bf16x8*>(&As[wr * 64 + a * 16 + (lane & 15)][ks * 32 + (lane >> 4) * 8]);
            #pragma unroll
            for (int b2 = 0; b2 < 4; ++b2)
                bfr[b2] = *reinterpret_cast<const bf16x8*>(&Bs[wc * 64 + b2 * 16 + (lane & 15)][ks * 32 + (lane >> 4) * 8]);
            #pragma unroll
            for (int a = 0; a < 4; ++a)
                #pragma unroll
                for (int b2 = 0; b2 < 4; ++b2)
                    acc[a][b2] = __builtin_amdgcn_mfma_f32_16x16x32_bf16(af[a], bfr[b2], acc[a][b2], 0, 0, 0);
        }
        __syncthreads();                 // reads done before next overwrite
    }
    #pragma unroll
    for (int a = 0; a < 4; ++a)
        #pragma unroll
        for (int b2 = 0; b2 < 4; ++b2)
            #pragma unroll
            for (int j = 0; j < 4; ++j) {
                int row = m0 + wr * 64 + a * 16 + (lane >> 4) * 4 + j;
                int col = n0 + wc * 64 + b2 * 16 + (lane & 15);
                outb[(size_t)row * EMBED + col] = __float2bfloat16(acc[a][b2][j]);
            }
}

// ---------------------------------------------------------------------------
// Masked exp-sum via 32x32x16 MFMA (fixed m=0: scores O(0.05), no overflow).
// One block = (b, h, 256 q rows, 512-k range); 4 waves own 64 q rows each
// (2 subtiles of 32). K staged 128 rows/iter in padded LDS [128][72].
// D layout (32x32): col = lane&31 -> q row (one q row per lane!);
// row = (reg&3)+8*(reg>>2)+4*(lane>>5) -> k row. Lane-local exp-sum, single
// shfl_xor(32) reduce. Diagonal handled in wave-uniform subtile branches.
// Partials (no atomics) to partial[row][KSPLIT].
// ---------------------------------------------------------------------------
__global__ __launch_bounds__(256, 4) void attn_sum_mfma(const bf16* __restrict__ q,
                                                        const bf16* __restrict__ k,
                                                        float* __restrict__ partial) {
    __shared__ __align__(16) bf16 Ks[128][72];
    const int tid  = threadIdx.x;
    const int lane = tid & 63;
    const int wave = tid >> 6;
    const int blk = blockIdx.x;          // (((b*16+h)*8)+qt)*KSPLIT + kt
    const int kt = blk & (KSPLIT - 1);
    const int qt = (blk >> 2) & 7;       // 8 q-tiles of 256 rows
    const int h  = (blk >> 5) & 15;
    const int b  = blk >> 9;
    const int n0 = qt * 256 + wave * 64; // this wave's 64 q rows
    const bf16* qbase = q + (size_t)(b * SEQ) * EMBED + h * HDIM;
    const bf16* kbase = k + (size_t)(b * SEQ) * EMBED + h * HDIM;

    // Q fragments: qf[qs][ks2]: row n0+qs*32+(lane&31), k = ks2*16+(lane>>5)*8
    bf16x8 qf[2][4];
    #pragma unroll
    for (int qs = 0; qs < 2; ++qs)
        #pragma unroll
        for (int ks2 = 0; ks2 < 4; ++ks2)
            qf[qs][ks2] = *reinterpret_cast<const bf16x8*>(
                &qbase[(size_t)(n0 + qs * 32 + (lane & 31)) * EMBED + ks2 * 16 + (lane >> 5) * 8]);

    f32x4 psv[2] = {};
    const int mbase = kt * (SEQ / KSPLIT);

    // staging: 128 rows x 64 cols per iter; 4x bf16x8 per thread
    const int sr = tid >> 3;             // base row 0..31 per chunk step of 32
    const int sc = (tid & 7) * 8;
    bf16x8 stg[4];
    #pragma unroll
    for (int c = 0; c < 4; ++c)
        stg[c] = *reinterpret_cast<const bf16x8*>(&kbase[(size_t)(mbase + c * 32 + sr) * EMBED + sc]);

    for (int it = 0; it < SEQ / KSPLIT / 128; ++it) {
        const int m0 = mbase + it * 128;
        __syncthreads();                 // prior Ks readers done
        #pragma unroll
        for (int c = 0; c < 4; ++c)
            *reinterpret_cast<bf16x8*>(&Ks[c * 32 + sr][sc]) = stg[c];
        __syncthreads();                 // Ks ready
        if (it + 1 < SEQ / KSPLIT / 128) {
            #pragma unroll
            for (int c = 0; c < 4; ++c)  // next tile; hides under compute (T14)
                stg[c] = *reinterpret_cast<const bf16x8*>(&kbase[(size_t)(m0 + 128 + c * 32 + sr) * EMBED + sc]);
        }

        #pragma unroll
        for (int t = 0; t < 4; ++t) {    // k subtiles of 32 rows
            bf16x8 kf[4];
            #pragma unroll
            for (int ks2 = 0; ks2 < 4; ++ks2)
                kf[ks2] = *reinterpret_cast<const bf16x8*>(
                    &Ks[t * 32 + (lane & 31)][ks2 * 16 + (lane >> 5) * 8]);
            #pragma unroll
            for (int qs = 0; qs < 2; ++qs) {
                f32x16 acc = {};
                #pragma unroll
                for (int ks2 = 0; ks2 < 4; ++ks2)
                    acc = __builtin_amdgcn_mfma_f32_32x32x16_bf16(kf[ks2], qf[qs][ks2], acc, 0, 0, 0);
                if ((m0 + t * 32) == (n0 + qs * 32)) {   // diagonal subtile
                    const int qcol = lane & 31;
                    #pragma unroll
                    for (int r = 0; r < 16; ++r) {
                        int crow = (r & 3) + 8 * (r >> 2) + 4 * (lane >> 5);
                        float e = fast_exp2(acc[r]);
                        psv[qs][r & 3] += (crow == qcol) ? 0.f : e;
                    }
                } else {
                    #pragma unroll
                    for (int r = 0; r < 16; ++r)
                        psv[qs][r & 3] += fast_exp2(acc[r]);
                }
            }
        }
    }

    #pragma unroll
    for (int qs = 0; qs < 2; ++qs) {
        float psum = (psv[qs][0] + psv[qs][1]) + (psv[qs][2] + psv[qs][3]);
        psum += __shfl_xor(psum, 32);    // lane l and l+32 hold same q row
        if (lane < 32) {
            size_t row = (size_t)(b * NHEADS + h) * SEQ + n0 + qs * 32 + lane;
            partial[row * KSPLIT + kt] = psum;
        }
    }
}

// ---------------------------------------------------------------------------
// lse = log(sum of KSPLIT partials) per row; energy = -sum(lse/beta)/(B*N).
// ---------------------------------------------------------------------------
__global__ __launch_bounds__(256) void finalize_kernel(const float* __restrict__ partial,
                                                       const float* __restrict__ betas,
                                                       float* __restrict__ out) {
    const int idx = blockIdx.x * 256 + threadIdx.x;    // 0..65535
    const float4 p = *reinterpret_cast<const float4*>(&partial[(size_t)idx * KSPLIT]);
    const int h = (idx >> 11) & 15;                    // idx = (b*16+h)*2048 + n
    float c = -logf(p.x + p.y + p.z + p.w) / (betas[h] * (float)(BATCH * SEQ));
    #pragma unroll
    for (int off = 1; off < 64; off <<= 1) c += __shfl_xor(c, off);
    __shared__ float ws[4];
    const int lane = threadIdx.x & 63, wave = threadIdx.x >> 6;
    if (lane == 0) ws[wave] = c;
    __syncthreads();
    if (threadIdx.x == 0) atomicAdd(out, ws[0] + ws[1] + ws[2] + ws[3]);
}

extern "C" void kernel_launch(void* const* d_in, const int* in_sizes, int n_in,
                              void* d_out, int out_size, void* d_ws, size_t ws_size,
                              hipStream_t stream) {
    const float* x     = (const float*)d_in[0];
    const float* wk    = (const float*)d_in[1];
    const float* wq    = (const float*)d_in[2];
    const float* betas = (const float*)d_in[3];
    float* out = (float*)d_out;

    const size_t NX = (size_t)BATCH * SEQ * EMBED;   // 4,194,304
    const size_t NW = (size_t)EMBED * EMBED;         // 1,048,576

    bf16* xb   = (bf16*)d_ws;                        // 8 MB
    bf16* wqb  = xb + NX;                            // 2 MB
    bf16* wkb  = wqb + NW;                           // 2 MB
    bf16* qb   = wkb + NW;                           // 8 MB
    bf16* kb   = qb + NX;                            // 8 MB
    float* prt = (float*)(kb + NX);                  // 1 MB: [B*H*SEQ][KSPLIT]

    prep_kernel<<<(int)((NX + 2 * NW) / 4 / 256), 256, 0, stream>>>(x, wq, wk, betas, xb, wqb, wkb, out);

    dim3 gproj(BATCH * SEQ / 128, 2 * EMBED / 128);  // (32, 16)
    proj_mfma<<<gproj, 256, 0, stream>>>(xb, wqb, wkb, qb, kb);

    attn_sum_mfma<<<BATCH * NHEADS * 8 * KSPLIT, 256, 0, stream>>>(qb, kb, prt);

    finalize_kernel<<<BATCH * NHEADS * SEQ / 256, 256, 0, stream>>>(prt, betas, out);
}